// Round 10
// baseline (196.448 us; speedup 1.0000x reference)
//
#include <hip/hip_runtime.h>
#include <hip/hip_bf16.h>
#include <float.h>

#define SS 4096
#define EE 64
#define DD 4096
#define CAP 128
#define SE (SS*EE)                    // 262144
#define ROW 8192                      // EE*CAP floats per token row
#define KS 16                         // split-K slices (256 k each)
#define BK 64                         // k sub-tile
static const size_t SEC = (size_t)SS * EE * CAP;  // 33554432

typedef unsigned long long u64;
typedef unsigned int u32;

#define GLOAD_LDS(g, l) __builtin_amdgcn_global_load_lds( \
    (const __attribute__((address_space(1))) unsigned int*)(g), \
    (__attribute__((address_space(3))) unsigned int*)(l), 16, 0, 0)

// ---------------- A: W transpose + zero flag arrays ----------------
__global__ __launch_bounds__(256) void k_prep(const float* __restrict__ W,
                                              float* __restrict__ Wt,
                                              u32* __restrict__ zbase) {
  int gid = blockIdx.x * 256 + threadIdx.x;
  if (gid < 64 + 2 * SS) zbase[gid] = 0u;

  __shared__ float t[64][65];
  int k0 = blockIdx.x * 64;
  int tid = threadIdx.x;
#pragma unroll
  for (int i = 0; i < 4; i++) {
    int f = tid + i * 256;
    int e = f >> 4, c4 = f & 15;
    float4 v = *(const float4*)(W + (size_t)e * DD + k0 + c4 * 4);
    t[e][c4 * 4 + 0] = v.x; t[e][c4 * 4 + 1] = v.y;
    t[e][c4 * 4 + 2] = v.z; t[e][c4 * 4 + 3] = v.w;
  }
  __syncthreads();
#pragma unroll
  for (int i = 0; i < 4; i++) {
    int f = tid + i * 256;
    int r = f >> 4, e4 = f & 15;
    float4 o;
    o.x = t[e4 * 4 + 0][r]; o.y = t[e4 * 4 + 1][r];
    o.z = t[e4 * 4 + 2][r]; o.w = t[e4 * 4 + 3][r];
    *(float4*)(Wt + (size_t)(k0 + r) * 64 + e4 * 4) = o;
  }
}

// ---------------- B: GEMM (4 waves) + zero-fill of d_out (1 wave) ----------------
// grid (64,16), 320 threads. Gemm waves: global_load_lds staging, swizzled xs.
// Fill wave: 256 f4 zero-stores into its block's 256KB slice of d_out,
// independent vmcnt (per-wave), 8 barrier segments matching the gemm path.
__global__ __launch_bounds__(320) void k_gf(const float* __restrict__ x,
                                            const float* __restrict__ Wt,
                                            float* __restrict__ part,
                                            float* __restrict__ out) {
  __shared__ float xs[64 * 64];    // [tok][k] with column-XOR swizzle, 16 KB
  __shared__ float wsh[64 * 64];   // [k][e] linear, 16 KB
  int tb = blockIdx.x;   // token tile (64 tokens)
  int ks = blockIdx.y;   // k slice (256 wide)
  int bid = blockIdx.y * 64 + blockIdx.x;   // 0..1023
  int tid = threadIdx.x;

  if (tid < 256) {
    // ---- gemm path (waves 0..3) ----
    int tx = tid & 15, ty = tid >> 4;
    int w = tid >> 6;
    int tyl = ty & 3;                 // swizzle key = (row>>2)&3 for rows ty*4+i
    float acc[4][4] = {};
#pragma unroll 1
    for (int kt = 0; kt < 4; kt++) {
      int k0 = ks * 256 + kt * BK;
      // stage via global_load_lds: per wave-iteration one contiguous 1KB chunk
#pragma unroll
      for (int i = 0; i < 4; i++) {
        int q = tid + i * 256;        // f4 slot 0..1023
        int r = q >> 4, c4 = q & 15;
        int cx = c4 ^ ((r >> 2) & 3); // column swizzle (bijective per row)
        int base = (i * 256 + w * 64) * 4;  // wave-uniform float offset
        GLOAD_LDS(x + (size_t)(tb * 64 + r) * DD + k0 + cx * 4, &xs[base]);
        GLOAD_LDS(Wt + (size_t)(k0 + r) * EE + c4 * 4, &wsh[base]);
      }
      __syncthreads();
#pragma unroll
      for (int k4 = 0; k4 < BK / 4; k4++) {
        float4 xv[4], wv[4];
        int xcol = (k4 ^ tyl) * 4;
#pragma unroll
        for (int i = 0; i < 4; i++)
          xv[i] = *(const float4*)&xs[(ty * 4 + i) * 64 + xcol];
#pragma unroll
        for (int kk = 0; kk < 4; kk++)
          wv[kk] = *(const float4*)&wsh[(k4 * 4 + kk) * 64 + tx * 4];
#pragma unroll
        for (int i = 0; i < 4; i++) {
          acc[i][0] += xv[i].x * wv[0].x + xv[i].y * wv[1].x + xv[i].z * wv[2].x + xv[i].w * wv[3].x;
          acc[i][1] += xv[i].x * wv[0].y + xv[i].y * wv[1].y + xv[i].z * wv[2].y + xv[i].w * wv[3].y;
          acc[i][2] += xv[i].x * wv[0].z + xv[i].y * wv[1].z + xv[i].z * wv[2].z + xv[i].w * wv[3].z;
          acc[i][3] += xv[i].x * wv[0].w + xv[i].y * wv[1].w + xv[i].z * wv[2].w + xv[i].w * wv[3].w;
        }
      }
      __syncthreads();
    }
#pragma unroll
    for (int i = 0; i < 4; i++) {
      *(float4*)(part + (((size_t)tb * 64 + ty * 4 + i) * KS + ks) * EE + tx * 4) =
          make_float4(acc[i][0], acc[i][1], acc[i][2], acc[i][3]);
    }
  } else {
    // ---- fill path (wave 4): zero 16384 f4 (256KB) of d_out ----
    int l = tid - 256;
    float4* zp = (float4*)out + (size_t)bid * 16384;
    const float4 zz = make_float4(0.f, 0.f, 0.f, 0.f);
    if (bid == 0 && l == 0) out[2 * SEC] = 0.f;
#pragma unroll 1
    for (int seg = 0; seg < 4; seg++) {
#pragma unroll
      for (int j = 0; j < 16; j++) zp[seg * 4096 + j * 64 + l] = zz;
      __syncthreads();
#pragma unroll
      for (int j = 16; j < 32; j++) zp[seg * 4096 + (j - 16) * 64 + l + 1024] = zz;
      __syncthreads();
      zp += 2048;
    }
  }
}

// ---------------- C: per-token softmax, top1 (gates), 2nd (logits), key ----------------
__global__ __launch_bounds__(256) void k_row(const float* __restrict__ part,
                                             const float* __restrict__ bias,
                                             float* __restrict__ gates,
                                             u64* __restrict__ keys,
                                             float2* __restrict__ g12,
                                             u32* __restrict__ cnt1) {
  int tid = threadIdx.x;
  int t = blockIdx.x * 4 + (tid >> 6);
  int e = tid & 63;
  const float* p = part + (size_t)t * KS * EE + e;
  float l = bias[e];
#pragma unroll
  for (int s = 0; s < KS; s++) l += p[s * EE];
  float m = l;
#pragma unroll
  for (int off = 32; off; off >>= 1) m = fmaxf(m, __shfl_xor(m, off));
  float ex = expf(l - m);
  float Z = ex;
#pragma unroll
  for (int off = 32; off; off >>= 1) Z += __shfl_xor(Z, off);
  float gate = ex / Z;
  gates[(size_t)t * 64 + e] = gate;
  float v1 = gate; int i1 = e;
#pragma unroll
  for (int off = 32; off; off >>= 1) {
    float ov = __shfl_xor(v1, off); int oi = __shfl_xor(i1, off);
    if (ov > v1 || (ov == v1 && oi < i1)) { v1 = ov; i1 = oi; }
  }
  float v2 = (e == i1) ? -FLT_MAX : l; int i2 = e;
#pragma unroll
  for (int off = 32; off; off >>= 1) {
    float ov = __shfl_xor(v2, off); int oi = __shfl_xor(i2, off);
    if (ov > v2 || (ov == v2 && oi < i2)) { v2 = ov; i2 = oi; }
  }
  float g1v = __shfl(gate, i1);
  float g2v = __shfl(gate, i2);
  if (e == 0) {
    u32 gb = __float_as_uint(v1);
    keys[t] = ((u64)(~gb) << 32) | ((u32)t << 12) | ((u32)i1 << 6) | (u32)i2;
    g12[t] = make_float2(g1v, g2v);
    atomicAdd(&cnt1[i1], 1u);
  }
}

// ---------------- D: pairwise rank counting + gates column partials ----------------
__global__ __launch_bounds__(256) void k_pc(const u64* __restrict__ keys,
                                            const float* __restrict__ gates,
                                            u32* __restrict__ r1a,
                                            u32* __restrict__ r2a,
                                            float* __restrict__ partial) {
  __shared__ u64 sk[256];
  int bid = blockIdx.x;
  int tid = threadIdx.x;
  if (bid < 256) {
    int bx = bid >> 4, by = bid & 15;
    sk[tid] = keys[by * 256 + tid];
    __syncthreads();
    int t = bx * 256 + tid;
    u64 myk = keys[t];
    u32 mye1 = (u32)((myk >> 6) & 63), mye2 = (u32)(myk & 63);
    u32 myt = (u32)t;
    u32 r1 = 0, r2 = 0;
    for (int j = 0; j < 256; j++) {
      u64 ks = sk[j];
      u32 se1 = (u32)((ks >> 6) & 63);
      u32 se2 = (u32)(ks & 63);
      u32 ss = (u32)((ks >> 12) & 4095);
      r1 += (se1 == mye1 && ks < myk) ? 1u : 0u;
      r2 += (se2 == mye2 && ss < myt) ? 1u : 0u;
    }
    if (r1) atomicAdd(&r1a[t], r1);
    if (r2) atomicAdd(&r2a[t], r2);
  } else {
    float* sh = (float*)sk;
    int b = bid - 256;
    int lane = tid & 63, w = tid >> 6;
    float s = 0.f;
#pragma unroll
    for (int i = 0; i < 16; i++) {
      int t = b * 64 + w * 16 + i;
      s += gates[(size_t)t * 64 + lane];
    }
    sh[tid] = s;
    __syncthreads();
    if (tid < 64) {
      float p = sh[tid] + sh[tid + 64] + sh[tid + 128] + sh[tid + 192];
      partial[b * 64 + tid] = p;
    }
  }
}

// ---------------- token slot info ----------------
__device__ __forceinline__ void load_tok(int tok,
    const u64* __restrict__ keys, const float2* __restrict__ g12,
    const u32* __restrict__ cnt1, const u32* __restrict__ r1a,
    const u32* __restrict__ r2a, int& o1, float& c1, int& o2, float& c2) {
  u64 k = keys[tok];
  int e1 = (int)((k >> 6) & 63), e2 = (int)(k & 63);
  u32 r1 = r1a[tok];
  u32 loc2 = cnt1[e2] + r2a[tok];
  float2 g = g12[tok];
  bool k1 = r1 < (u32)CAP;
  bool k2 = loc2 < (u32)CAP;
  float g1 = k1 ? g.x : 0.f;
  float g2 = k2 ? g.y : 0.f;
  float den = fmaxf(g1 + g2, 1.1920929e-07f);
  c1 = g1 / den;
  c2 = g2 / den;
  o1 = k1 ? e1 * CAP + (int)r1 : -1;
  o2 = k2 ? e2 * CAP + (int)loc2 : -1;
}

// ---------------- E: sparse scatter + l_aux (over pre-zeroed d_out) ----------------
__global__ __launch_bounds__(256) void k_fin(const u64* __restrict__ keys,
                                             const float2* __restrict__ g12,
                                             const u32* __restrict__ cnt1,
                                             const u32* __restrict__ r1a,
                                             const u32* __restrict__ r2a,
                                             const float* __restrict__ partial,
                                             float* __restrict__ out) {
  __shared__ float sh[256];
  int bid = blockIdx.x;
  int tid = threadIdx.x;
  if (bid < 16) {
    int t = bid * 256 + tid;
    int o1, o2; float c1, c2;
    load_tok(t, keys, g12, cnt1, r1a, r2a, o1, c1, o2, c2);
    float* comb = out + 1;
    float* disp = out + 1 + SEC;
    size_t base = (size_t)t * ROW;
    if (o1 >= 0) { comb[base + o1] = c1; disp[base + o1] = 1.f; }
    if (o2 >= 0) { comb[base + o2] = c2; disp[base + o2] = 1.f; }
  } else {
    int e = tid & 63, q = tid >> 6;
    float s = 0.f;
#pragma unroll
    for (int b = 0; b < 16; b++) s += partial[(q * 16 + b) * 64 + e];
    sh[tid] = s;
    __syncthreads();
    if (tid < 64) {
      float colsum = sh[tid] + sh[tid + 64] + sh[tid + 128] + sh[tid + 192];
      float me = colsum * (1.0f / SS);
      float ce = (float)cnt1[tid] * (1.0f / SS);
      float term = me * ce;
#pragma unroll
      for (int off = 32; off; off >>= 1) term += __shfl_xor(term, off);
      if (tid == 0) out[0] = term * (float)EE * 0.01f;
    }
  }
}

extern "C" void kernel_launch(void* const* d_in, const int* in_sizes, int n_in,
                              void* d_out, int out_size, void* d_ws, size_t ws_size,
                              hipStream_t stream) {
  const float* x = (const float*)d_in[0];
  const float* W = (const float*)d_in[1];
  const float* bias = (const float*)d_in[2];
  float* out = (float*)d_out;

  // workspace layout
  float* Wt = (float*)d_ws;                     // 262144 floats (1 MB)
  float* part = Wt + 262144;                    // SS*KS*EE = 4194304 floats (16 MB)
  float* gates = part + (size_t)SS * KS * EE;   // 262144 floats (1 MB)
  u64* keys = (u64*)(gates + (size_t)SE);       // 4096 u64
  float2* g12 = (float2*)(keys + SS);           // 4096 float2
  u32* cnt1 = (u32*)(g12 + SS);                 // 64
  u32* r1a = cnt1 + 64;                         // 4096
  u32* r2a = r1a + SS;                          // 4096
  float* partial = (float*)(r2a + SS);          // 64*64 floats

  k_prep<<<64, 256, 0, stream>>>(W, Wt, cnt1);
  k_gf<<<dim3(64, KS), 320, 0, stream>>>(x, Wt, part, out);
  k_row<<<SS / 4, 256, 0, stream>>>(part, bias, gates, keys, g12, cnt1);
  k_pc<<<320, 256, 0, stream>>>(keys, gates, r1a, r2a, partial);
  k_fin<<<17, 256, 0, stream>>>(keys, g12, cnt1, r1a, r2a, partial, out);
}